// Round 2
// baseline (734.165 us; speedup 1.0000x reference)
//
#include <hip/hip_runtime.h>
#include <math.h>

typedef unsigned short u16;
typedef short s16x8 __attribute__((ext_vector_type(8)));   // 8 bf16 (4 VGPRs)
typedef float f32x4 __attribute__((ext_vector_type(4)));   // 4 fp32 acc

static constexpr int Cc = 256;
static constexpr int Ll = 4096;
static constexpr int Bb = 4;

__device__ __forceinline__ u16 f2b(float f) {
    union { float f; unsigned u; } v; v.f = f;
    unsigned r = v.u + 0x7FFF + ((v.u >> 16) & 1);   // RNE
    return (u16)(r >> 16);
}

// ---------------- Kernel 1: BN stats -> folded affine coefs ----------------
__global__ void k_stats(const float* __restrict__ x, const float* __restrict__ gamma,
                        const float* __restrict__ beta, float* __restrict__ coefA,
                        float* __restrict__ coefB) {
    int c = blockIdx.x, t = threadIdx.x;
    float s = 0.f, s2 = 0.f;
    for (int idx = t; idx < Bb * Ll; idx += 256) {
        int b = idx >> 12, l = idx & (Ll - 1);
        float v = x[(size_t)(b * Cc + c) * Ll + l];
        s += v; s2 += v * v;
    }
    __shared__ float rs[256], rs2[256];
    rs[t] = s; rs2[t] = s2; __syncthreads();
    for (int off = 128; off > 0; off >>= 1) {
        if (t < off) { rs[t] += rs[t + off]; rs2[t] += rs2[t + off]; }
        __syncthreads();
    }
    if (t == 0) {
        float mean = rs[0] / (Bb * Ll);
        float var  = rs2[0] / (Bb * Ll) - mean * mean;   // biased, as torch BN
        float rstd = rsqrtf(var + 1e-5f);
        float a = gamma[c] * rstd;
        coefA[c] = a;
        coefB[c] = beta[c] - mean * a;
    }
}

// ---------------- Kernel 2: fold BN into weights, convert bf16 ----------------
// rows 0..255 q (x scale*log2e), 256..511 k, 512..767 v, 768..1023 wp passthrough
__global__ void k_fold(const float* __restrict__ wq, const float* __restrict__ bq,
                       const float* __restrict__ wk, const float* __restrict__ bk,
                       const float* __restrict__ wv, const float* __restrict__ bv,
                       const float* __restrict__ wp,
                       const float* __restrict__ coefA, const float* __restrict__ coefB,
                       u16* __restrict__ Wqkv, float* __restrict__ biasQKV,
                       u16* __restrict__ Wp16) {
    int m = blockIdx.x, t = threadIdx.x;
    if (m >= 768) {
        int row = m - 768;
        Wp16[row * Cc + t] = f2b(wp[row * Cc + t]);
        return;
    }
    int type = m >> 8, row = m & 255;
    const float* W  = (type == 0) ? wq : (type == 1) ? wk : wv;
    const float* bs = (type == 0) ? bq : (type == 1) ? bk : bv;
    float wval = W[row * Cc + t];
    float s2 = (type == 0) ? 0.09016844005556021f : 1.0f;  // (1/sqrt(C)) * log2(e)
    Wqkv[m * Cc + t] = f2b(wval * coefA[t] * s2);
    __shared__ float rs[256];
    rs[t] = wval * coefB[t];
    __syncthreads();
    for (int off = 128; off > 0; off >>= 1) {
        if (t < off) rs[t] += rs[t + off];
        __syncthreads();
    }
    if (t == 0) biasQKV[m] = (bs[row] + rs[0]) * s2;
}

// ---------------- Kernel 3: x [B][C][L] fp32 -> XT [B][L][C] bf16 ----------------
__global__ void k_transpose(const float* __restrict__ x, u16* __restrict__ XT) {
    int lt = blockIdx.x, ct = blockIdx.y, b = blockIdx.z, t = threadIdx.x;
    int l0 = lt * 64, c0 = ct * 64;
    __shared__ u16 tile[64][65];
    int ll = t & 63, cb = t >> 6;
    #pragma unroll
    for (int rep = 0; rep < 16; rep++) {
        int cl = cb * 16 + rep;
        tile[cl][ll] = f2b(x[(size_t)(b * Cc + c0 + cl) * Ll + l0 + ll]);
    }
    __syncthreads();
    int cl2 = t & 63, lb = t >> 6;
    #pragma unroll
    for (int rep = 0; rep < 16; rep++) {
        int ll2 = lb * 16 + rep;
        XT[(size_t)(b * Ll + l0 + ll2) * Cc + c0 + cl2] = tile[cl2][ll2];
    }
}

// ---------------- Kernel 4: QKV GEMM -> QT,KT [B][L][C], V [B][C][L] (all bf16) --
__launch_bounds__(256, 1)
__global__ void k_qkv(const u16* __restrict__ XT, const u16* __restrict__ Wqkv,
                      const float* __restrict__ biasQKV,
                      u16* __restrict__ QT, u16* __restrict__ KT, u16* __restrict__ V) {
    int ox = blockIdx.x, ly = blockIdx.y, b = blockIdx.z;
    int t = threadIdx.x, w = t >> 6, lane = t & 63;
    int l16 = lane & 15, quad = lane >> 4;
    int o0 = ox * 64, l0 = ly * 64;
    __shared__ u16 Xs[64][264];   // pad 256->264 u16
    {
        int row = t >> 2, chunk = t & 3;
        const u16* src = XT + (size_t)(b * Ll + l0 + row) * Cc + chunk * 64;
        u16* dst = &Xs[row][chunk * 64];
        #pragma unroll
        for (int u = 0; u < 8; u++)          // 8 x 8 u16 = 64 u16 (FIXED: was 4 x stride-16)
            *(uint4*)(dst + u * 8) = *(const uint4*)(src + u * 8);
    }
    // preload A frags (Wqkv rows hot in L2)
    s16x8 af[8];
    {
        const u16* wrow = Wqkv + (size_t)(o0 + w * 16 + l16) * Cc + quad * 8;
        #pragma unroll
        for (int ks = 0; ks < 8; ks++) af[ks] = *(const s16x8*)(wrow + ks * 32);
    }
    __syncthreads();
    f32x4 acc[4];
    #pragma unroll
    for (int ns = 0; ns < 4; ns++)
        #pragma unroll
        for (int r = 0; r < 4; r++) acc[ns][r] = 0.f;
    #pragma unroll
    for (int ks = 0; ks < 8; ks++) {
        #pragma unroll
        for (int ns = 0; ns < 4; ns++) {
            s16x8 bf = *(const s16x8*)(&Xs[ns * 16 + l16][ks * 32 + quad * 8]);
            acc[ns] = __builtin_amdgcn_mfma_f32_16x16x32_bf16(af[ks], bf, acc[ns], 0, 0, 0);
        }
    }
    int obase = o0 + w * 16 + quad * 4;
    float bias[4];
    #pragma unroll
    for (int r = 0; r < 4; r++) bias[r] = biasQKV[obase + r];
    #pragma unroll
    for (int ns = 0; ns < 4; ns++) {
        int l = l0 + ns * 16 + l16;
        if (ox < 8) {   // q or k -> transposed [L][C] layout, 4 consecutive o per lane
            u16* dstbase = (ox < 4) ? QT : KT;
            int oo = obase - ((ox < 4) ? 0 : 256);
            ushort4 pk;
            pk.x = f2b(acc[ns][0] + bias[0]);
            pk.y = f2b(acc[ns][1] + bias[1]);
            pk.z = f2b(acc[ns][2] + bias[2]);
            pk.w = f2b(acc[ns][3] + bias[3]);
            *(ushort4*)(dstbase + (size_t)(b * Ll + l) * Cc + oo) = pk;
        } else {        // v -> natural [C][L]
            #pragma unroll
            for (int r = 0; r < 4; r++) {
                int o = obase + r - 512;
                V[(size_t)(b * Cc + o) * Ll + l] = f2b(acc[ns][r] + bias[r]);
            }
        }
    }
}

// ---------------- Kernel 5: flash attention -> OT [B][L][C] bf16 ----------------
// 256 blocks (b x 64 i-tiles), 4 waves x 16 rows. Q in regs; K/V frags direct from
// global (L2-resident); P through wave-private LDS (C/D -> A layout).
__launch_bounds__(256, 1)
__global__ void k_attn(const u16* __restrict__ QT, const u16* __restrict__ KT,
                       const u16* __restrict__ V, u16* __restrict__ OT) {
    int id = blockIdx.x;
    // XCD swizzle: 2 XCDs per batch so K+V (4MB/batch) stays L2-resident
    int xcd = id & 7, local = id >> 3;
    int b = xcd >> 1;
    int itile = local * 2 + (xcd & 1);
    int t = threadIdx.x, w = t >> 6, lane = t & 63;
    int l16 = lane & 15, quad = lane >> 4;
    int i0 = itile * 64 + w * 16;
    __shared__ u16 Ps[4][16][72];   // per-wave P tile, pad 64->72

    s16x8 qf[8];
    const u16* qrow = QT + (size_t)(b * Ll + i0 + l16) * Cc + quad * 8;
    #pragma unroll
    for (int ks = 0; ks < 8; ks++) qf[ks] = *(const s16x8*)(qrow + ks * 32);

    f32x4 of[16];
    #pragma unroll
    for (int nc = 0; nc < 16; nc++)
        #pragma unroll
        for (int r = 0; r < 4; r++) of[nc][r] = 0.f;
    float m_run[4], l_run[4];
    #pragma unroll
    for (int r = 0; r < 4; r++) { m_run[r] = -INFINITY; l_run[r] = 0.f; }

    const u16* Kbase = KT + (size_t)b * Ll * Cc;
    const u16* Vbase = V + (size_t)b * Cc * Ll;

    for (int jt = 0; jt < 64; jt++) {
        int j0 = jt * 64;
        // ---- S = Q^T K (logits already scaled by 1/16*log2e via Wq fold) ----
        f32x4 sf[4];
        #pragma unroll
        for (int ns = 0; ns < 4; ns++)
            #pragma unroll
            for (int r = 0; r < 4; r++) sf[ns][r] = 0.f;
        #pragma unroll
        for (int ks = 0; ks < 8; ks++) {
            #pragma unroll
            for (int ns = 0; ns < 4; ns++) {
                s16x8 bf = *(const s16x8*)(Kbase + (size_t)(j0 + ns * 16 + l16) * Cc + ks * 32 + quad * 8);
                sf[ns] = __builtin_amdgcn_mfma_f32_16x16x32_bf16(qf[ks], bf, sf[ns], 0, 0, 0);
            }
        }
        // ---- online softmax (rows i = quad*4+r; 16 cols live in the quad's lanes) --
        float pv[4][4];
        #pragma unroll
        for (int r = 0; r < 4; r++) {
            float tm = fmaxf(fmaxf(sf[0][r], sf[1][r]), fmaxf(sf[2][r], sf[3][r]));
            #pragma unroll
            for (int off = 8; off > 0; off >>= 1) tm = fmaxf(tm, __shfl_xor(tm, off));
            float mnew = fmaxf(m_run[r], tm);
            float alpha = exp2f(m_run[r] - mnew);
            float rsum = 0.f;
            #pragma unroll
            for (int ns = 0; ns < 4; ns++) {
                float p = exp2f(sf[ns][r] - mnew);
                pv[ns][r] = p; rsum += p;
            }
            #pragma unroll
            for (int off = 8; off > 0; off >>= 1) rsum += __shfl_xor(rsum, off);
            l_run[r] = l_run[r] * alpha + rsum;
            m_run[r] = mnew;
            #pragma unroll
            for (int nc = 0; nc < 16; nc++) of[nc][r] *= alpha;
        }
        // ---- P: C/D layout -> LDS -> A layout ----
        #pragma unroll
        for (int ns = 0; ns < 4; ns++)
            #pragma unroll
            for (int r = 0; r < 4; r++)
                Ps[w][quad * 4 + r][ns * 16 + l16] = f2b(pv[ns][r]);
        __syncthreads();   // correctness-first; wave-private DS ordering revisit later
        // ---- O += P * V^T ----
        #pragma unroll
        for (int ks2 = 0; ks2 < 2; ks2++) {
            s16x8 pa = *(const s16x8*)(&Ps[w][l16][ks2 * 32 + quad * 8]);
            #pragma unroll
            for (int nc = 0; nc < 16; nc++) {
                s16x8 bf = *(const s16x8*)(Vbase + (size_t)(nc * 16 + l16) * Ll + j0 + ks2 * 32 + quad * 8);
                of[nc] = __builtin_amdgcn_mfma_f32_16x16x32_bf16(pa, bf, of[nc], 0, 0, 0);
            }
        }
        __syncthreads();   // keep waves from overwriting Ps before all reads done (uniform)
    }
    float inv[4];
    #pragma unroll
    for (int r = 0; r < 4; r++) inv[r] = 1.f / l_run[r];
    #pragma unroll
    for (int nc = 0; nc < 16; nc++)
        #pragma unroll
        for (int r = 0; r < 4; r++)
            OT[(size_t)(b * Ll + i0 + quad * 4 + r) * Cc + nc * 16 + l16] = f2b(of[nc][r] * inv[r]);
}

// ---------------- Kernel 6: projection + bias + residual -> out fp32 ----------------
__launch_bounds__(256, 1)
__global__ void k_proj(const u16* __restrict__ OT, const u16* __restrict__ Wp16,
                       const float* __restrict__ bp, const float* __restrict__ x,
                       float* __restrict__ out) {
    int ox = blockIdx.x, ly = blockIdx.y, b = blockIdx.z;
    int t = threadIdx.x, w = t >> 6, lane = t & 63;
    int l16 = lane & 15, quad = lane >> 4;
    int o0 = ox * 64, l0 = ly * 64;
    __shared__ u16 Os[64][264];
    {
        int row = t >> 2, chunk = t & 3;
        const u16* src = OT + (size_t)(b * Ll + l0 + row) * Cc + chunk * 64;
        u16* dst = &Os[row][chunk * 64];
        #pragma unroll
        for (int u = 0; u < 8; u++)          // FIXED: full 64 u16 per thread
            *(uint4*)(dst + u * 8) = *(const uint4*)(src + u * 8);
    }
    s16x8 af[8];
    {
        const u16* wrow = Wp16 + (size_t)(o0 + w * 16 + l16) * Cc + quad * 8;
        #pragma unroll
        for (int ks = 0; ks < 8; ks++) af[ks] = *(const s16x8*)(wrow + ks * 32);
    }
    __syncthreads();
    f32x4 acc[4];
    #pragma unroll
    for (int ns = 0; ns < 4; ns++)
        #pragma unroll
        for (int r = 0; r < 4; r++) acc[ns][r] = 0.f;
    #pragma unroll
    for (int ks = 0; ks < 8; ks++) {
        #pragma unroll
        for (int ns = 0; ns < 4; ns++) {
            s16x8 bf = *(const s16x8*)(&Os[ns * 16 + l16][ks * 32 + quad * 8]);
            acc[ns] = __builtin_amdgcn_mfma_f32_16x16x32_bf16(af[ks], bf, acc[ns], 0, 0, 0);
        }
    }
    int ob = o0 + w * 16 + quad * 4;
    float bias[4];
    #pragma unroll
    for (int r = 0; r < 4; r++) bias[r] = bp[ob + r];
    #pragma unroll
    for (int ns = 0; ns < 4; ns++) {
        #pragma unroll
        for (int r = 0; r < 4; r++) {
            int o = ob + r;
            int l = l0 + ns * 16 + l16;
            size_t idx = (size_t)(b * Cc + o) * Ll + l;
            out[idx] = x[idx] + bias[r] + acc[ns][r];
        }
    }
}

// ---------------- launch ----------------
extern "C" void kernel_launch(void* const* d_in, const int* in_sizes, int n_in,
                              void* d_out, int out_size, void* d_ws, size_t ws_size,
                              hipStream_t stream) {
    const float* x     = (const float*)d_in[0];
    const float* gamma = (const float*)d_in[1];
    const float* beta  = (const float*)d_in[2];
    const float* wq    = (const float*)d_in[3];
    const float* bq    = (const float*)d_in[4];
    const float* wk    = (const float*)d_in[5];
    const float* bk    = (const float*)d_in[6];
    const float* wv    = (const float*)d_in[7];
    const float* bv    = (const float*)d_in[8];
    const float* wp    = (const float*)d_in[9];
    const float* bp    = (const float*)d_in[10];
    float* out = (float*)d_out;
    char* ws = (char*)d_ws;

    float* coefA   = (float*)(ws + 0);         // 256 f32
    float* coefB   = (float*)(ws + 1024);      // 256 f32
    float* biasQKV = (float*)(ws + 2048);      // 768 f32
    u16*   Wqkv    = (u16*)(ws + 8192);        // 768x256 bf16
    u16*   Wp16    = (u16*)(ws + 401408);      // 256x256 bf16
    u16*   XT      = (u16*)(ws + 532480);      // [B][L][C] bf16 (8.39MB)
    u16*   QT      = (u16*)(ws + 8921088);     // [B][L][C] bf16
    u16*   KT      = (u16*)(ws + 17309696);    // [B][L][C] bf16
    u16*   V       = (u16*)(ws + 25698304);    // [B][C][L] bf16
    u16*   OT      = XT;                       // alias: XT dead after k_qkv

    k_stats<<<256, 256, 0, stream>>>(x, gamma, beta, coefA, coefB);
    k_fold<<<1024, 256, 0, stream>>>(wq, bq, wk, bk, wv, bv, wp, coefA, coefB,
                                     Wqkv, biasQKV, Wp16);
    k_transpose<<<dim3(64, 4, 4), 256, 0, stream>>>(x, XT);
    k_qkv<<<dim3(12, 64, 4), 256, 0, stream>>>(XT, Wqkv, biasQKV, QT, KT, V);
    k_attn<<<256, 256, 0, stream>>>(QT, KT, V, OT);
    k_proj<<<dim3(4, 64, 4), 256, 0, stream>>>(OT, Wp16, bp, x, out);
}

// Round 3
// 516.260 us; speedup vs baseline: 1.4221x; 1.4221x over previous
//
#include <hip/hip_runtime.h>
#include <math.h>

typedef unsigned short u16;
typedef short s16x8 __attribute__((ext_vector_type(8)));   // 8 bf16 (4 VGPRs)
typedef float f32x4 __attribute__((ext_vector_type(4)));   // 4 fp32 acc

static constexpr int Cc = 256;
static constexpr int Ll = 4096;
static constexpr int Bb = 4;

__device__ __forceinline__ u16 f2b(float f) {
    union { float f; unsigned u; } v; v.f = f;
    unsigned r = v.u + 0x7FFF + ((v.u >> 16) & 1);   // RNE
    return (u16)(r >> 16);
}

// ---------------- Kernel 1: BN stats -> folded affine coefs ----------------
__global__ void k_stats(const float* __restrict__ x, const float* __restrict__ gamma,
                        const float* __restrict__ beta, float* __restrict__ coefA,
                        float* __restrict__ coefB) {
    int c = blockIdx.x, t = threadIdx.x;
    float s = 0.f, s2 = 0.f;
    for (int idx = t; idx < Bb * Ll; idx += 256) {
        int b = idx >> 12, l = idx & (Ll - 1);
        float v = x[(size_t)(b * Cc + c) * Ll + l];
        s += v; s2 += v * v;
    }
    __shared__ float rs[256], rs2[256];
    rs[t] = s; rs2[t] = s2; __syncthreads();
    for (int off = 128; off > 0; off >>= 1) {
        if (t < off) { rs[t] += rs[t + off]; rs2[t] += rs2[t + off]; }
        __syncthreads();
    }
    if (t == 0) {
        float mean = rs[0] / (Bb * Ll);
        float var  = rs2[0] / (Bb * Ll) - mean * mean;   // biased, as torch BN
        float rstd = rsqrtf(var + 1e-5f);
        float a = gamma[c] * rstd;
        coefA[c] = a;
        coefB[c] = beta[c] - mean * a;
    }
}

// ---------------- Kernel 2: fold BN into weights, convert bf16 ----------------
__global__ void k_fold(const float* __restrict__ wq, const float* __restrict__ bq,
                       const float* __restrict__ wk, const float* __restrict__ bk,
                       const float* __restrict__ wv, const float* __restrict__ bv,
                       const float* __restrict__ wp,
                       const float* __restrict__ coefA, const float* __restrict__ coefB,
                       u16* __restrict__ Wqkv, float* __restrict__ biasQKV,
                       u16* __restrict__ Wp16) {
    int m = blockIdx.x, t = threadIdx.x;
    if (m >= 768) {
        int row = m - 768;
        Wp16[row * Cc + t] = f2b(wp[row * Cc + t]);
        return;
    }
    int type = m >> 8, row = m & 255;
    const float* W  = (type == 0) ? wq : (type == 1) ? wk : wv;
    const float* bs = (type == 0) ? bq : (type == 1) ? bk : bv;
    float wval = W[row * Cc + t];
    float s2 = (type == 0) ? 0.09016844005556021f : 1.0f;  // (1/sqrt(C)) * log2(e)
    Wqkv[m * Cc + t] = f2b(wval * coefA[t] * s2);
    __shared__ float rs[256];
    rs[t] = wval * coefB[t];
    __syncthreads();
    for (int off = 128; off > 0; off >>= 1) {
        if (t < off) rs[t] += rs[t + off];
        __syncthreads();
    }
    if (t == 0) biasQKV[m] = (bs[row] + rs[0]) * s2;
}

// ---------------- Kernel 3: x [B][C][L] fp32 -> XT [B][L][C] bf16 ----------------
__global__ void k_transpose(const float* __restrict__ x, u16* __restrict__ XT) {
    int lt = blockIdx.x, ct = blockIdx.y, b = blockIdx.z, t = threadIdx.x;
    int l0 = lt * 64, c0 = ct * 64;
    __shared__ u16 tile[64][65];
    int ll = t & 63, cb = t >> 6;
    #pragma unroll
    for (int rep = 0; rep < 16; rep++) {
        int cl = cb * 16 + rep;
        tile[cl][ll] = f2b(x[(size_t)(b * Cc + c0 + cl) * Ll + l0 + ll]);
    }
    __syncthreads();
    int cl2 = t & 63, lb = t >> 6;
    #pragma unroll
    for (int rep = 0; rep < 16; rep++) {
        int ll2 = lb * 16 + rep;
        XT[(size_t)(b * Ll + l0 + ll2) * Cc + c0 + cl2] = tile[cl2][ll2];
    }
}

// ---------------- Kernel 4: QKV GEMM -> QT,KT [B][L][C], V [B][C][L] (all bf16) --
__launch_bounds__(256, 1)
__global__ void k_qkv(const u16* __restrict__ XT, const u16* __restrict__ Wqkv,
                      const float* __restrict__ biasQKV,
                      u16* __restrict__ QT, u16* __restrict__ KT, u16* __restrict__ V) {
    int ox = blockIdx.x, ly = blockIdx.y, b = blockIdx.z;
    int t = threadIdx.x, w = t >> 6, lane = t & 63;
    int l16 = lane & 15, quad = lane >> 4;
    int o0 = ox * 64, l0 = ly * 64;
    __shared__ u16 Xs[64][264];
    {
        int row = t >> 2, chunk = t & 3;
        const u16* src = XT + (size_t)(b * Ll + l0 + row) * Cc + chunk * 64;
        u16* dst = &Xs[row][chunk * 64];
        #pragma unroll
        for (int u = 0; u < 8; u++)
            *(uint4*)(dst + u * 8) = *(const uint4*)(src + u * 8);
    }
    s16x8 af[8];
    {
        const u16* wrow = Wqkv + (size_t)(o0 + w * 16 + l16) * Cc + quad * 8;
        #pragma unroll
        for (int ks = 0; ks < 8; ks++) af[ks] = *(const s16x8*)(wrow + ks * 32);
    }
    __syncthreads();
    f32x4 acc[4];
    #pragma unroll
    for (int ns = 0; ns < 4; ns++)
        #pragma unroll
        for (int r = 0; r < 4; r++) acc[ns][r] = 0.f;
    #pragma unroll
    for (int ks = 0; ks < 8; ks++) {
        #pragma unroll
        for (int ns = 0; ns < 4; ns++) {
            s16x8 bf = *(const s16x8*)(&Xs[ns * 16 + l16][ks * 32 + quad * 8]);
            acc[ns] = __builtin_amdgcn_mfma_f32_16x16x32_bf16(af[ks], bf, acc[ns], 0, 0, 0);
        }
    }
    int obase = o0 + w * 16 + quad * 4;
    float bias[4];
    #pragma unroll
    for (int r = 0; r < 4; r++) bias[r] = biasQKV[obase + r];
    #pragma unroll
    for (int ns = 0; ns < 4; ns++) {
        int l = l0 + ns * 16 + l16;
        if (ox < 8) {
            u16* dstbase = (ox < 4) ? QT : KT;
            int oo = obase - ((ox < 4) ? 0 : 256);
            ushort4 pk;
            pk.x = f2b(acc[ns][0] + bias[0]);
            pk.y = f2b(acc[ns][1] + bias[1]);
            pk.z = f2b(acc[ns][2] + bias[2]);
            pk.w = f2b(acc[ns][3] + bias[3]);
            *(ushort4*)(dstbase + (size_t)(b * Ll + l) * Cc + oo) = pk;
        } else {
            #pragma unroll
            for (int r = 0; r < 4; r++) {
                int o = obase + r - 512;
                V[(size_t)(b * Cc + o) * Ll + l] = f2b(acc[ns][r] + bias[r]);
            }
        }
    }
}

// ---------------- Kernel 5: flash attention -> OT [B][L][C] bf16 ----------------
// 256 blocks (b x 64 i-tiles), 4 waves x 16 rows.
// K/V tiles cooperatively staged ONCE per block into LDS in fragment-permuted
// order (lane-linear ds_write_b128 AND ds_read_b128 -> zero bank conflicts),
// prefetched one jt ahead into VGPRs. P through wave-private LDS.
__launch_bounds__(256, 1)
__global__ void k_attn(const u16* __restrict__ QT, const u16* __restrict__ KT,
                       const u16* __restrict__ V, u16* __restrict__ OT) {
    int id = blockIdx.x;
    int xcd = id & 7, local = id >> 3;
    int b = xcd >> 1;
    int itile = local * 2 + (xcd & 1);
    int t = threadIdx.x, w = t >> 6, lane = t & 63;
    int l16 = lane & 15, quad = lane >> 4;
    int i0 = itile * 64 + w * 16;

    __shared__ u16 Ks[2048 * 8];    // 32KB, fragment-permuted K-tile
    __shared__ u16 Vs[2048 * 8];    // 32KB, fragment-permuted V-tile
    __shared__ u16 Ps[4][16][72];   // per-wave P round-trip

    // Q fragments (A-layout) in registers
    s16x8 qf[8];
    {
        const u16* qrow = QT + (size_t)(b * Ll + i0 + l16) * Cc + quad * 8;
        #pragma unroll
        for (int ks = 0; ks < 8; ks++) qf[ks] = *(const s16x8*)(qrow + ks * 32);
    }

    // Prefetch base addresses (chunk p = R*256 + t; g = p>>6 = R*4+w):
    //  K round R: ns=(R*4+w)>>3, ks=(R*4+w)&7 -> row jl=ns*16+l16, col c0=ks*32+quad*8
    //  V round R: nc=(R*4+w)>>1, ks2=(R*4+w)&1 -> row c=nc*16+l16, col jl=ks2*32+quad*8
    const u16* Kb = KT + (size_t)b * Ll * Cc;
    const u16* Vb = V + (size_t)b * Cc * Ll;
    size_t koff[8], voff[8];
    #pragma unroll
    for (int R = 0; R < 8; R++) {
        int g = R * 4 + w;
        int ns = g >> 3, ks = g & 7;
        koff[R] = (size_t)(ns * 16 + l16) * Cc + ks * 32 + quad * 8;
        int nc = g >> 1, ks2 = g & 1;
        voff[R] = (size_t)(nc * 16 + l16) * Ll + ks2 * 32 + quad * 8;
    }

    uint4 pf[16];
    #pragma unroll
    for (int R = 0; R < 8; R++) {
        pf[R]     = *(const uint4*)(Kb + koff[R]);        // j0 = 0
        pf[8 + R] = *(const uint4*)(Vb + voff[R]);
    }

    f32x4 of[16];
    #pragma unroll
    for (int nc = 0; nc < 16; nc++)
        #pragma unroll
        for (int r = 0; r < 4; r++) of[nc][r] = 0.f;
    float m_run[4], l_run[4];
    #pragma unroll
    for (int r = 0; r < 4; r++) { m_run[r] = -INFINITY; l_run[r] = 0.f; }

    for (int jt = 0; jt < 64; jt++) {
        // ---- commit prefetched tiles to LDS (lane-linear, conflict-free) ----
        #pragma unroll
        for (int R = 0; R < 8; R++) {
            *(uint4*)(&Ks[(size_t)(R * 256 + t) * 8]) = pf[R];
            *(uint4*)(&Vs[(size_t)(R * 256 + t) * 8]) = pf[8 + R];
        }
        __syncthreads();
        // ---- prefetch next jt while computing this one ----
        if (jt < 63) {
            size_t j0n = (size_t)(jt + 1) * 64;
            #pragma unroll
            for (int R = 0; R < 8; R++) {
                pf[R]     = *(const uint4*)(Kb + j0n * Cc + koff[R]);
                pf[8 + R] = *(const uint4*)(Vb + j0n + voff[R]);
            }
        }
        // ---- S = Q K^T (scale*log2e folded into Wq) ----
        f32x4 sf[4];
        #pragma unroll
        for (int ns = 0; ns < 4; ns++)
            #pragma unroll
            for (int r = 0; r < 4; r++) sf[ns][r] = 0.f;
        #pragma unroll
        for (int ks = 0; ks < 8; ks++) {
            #pragma unroll
            for (int ns = 0; ns < 4; ns++) {
                s16x8 bf = *(const s16x8*)(&Ks[(size_t)((ns * 8 + ks) * 64 + lane) * 8]);
                sf[ns] = __builtin_amdgcn_mfma_f32_16x16x32_bf16(qf[ks], bf, sf[ns], 0, 0, 0);
            }
        }
        // ---- online softmax ----
        float pv[4][4];
        #pragma unroll
        for (int r = 0; r < 4; r++) {
            float tm = fmaxf(fmaxf(sf[0][r], sf[1][r]), fmaxf(sf[2][r], sf[3][r]));
            #pragma unroll
            for (int off = 8; off > 0; off >>= 1) tm = fmaxf(tm, __shfl_xor(tm, off));
            float mnew = fmaxf(m_run[r], tm);
            float alpha = exp2f(m_run[r] - mnew);
            float rsum = 0.f;
            #pragma unroll
            for (int ns = 0; ns < 4; ns++) {
                float p = exp2f(sf[ns][r] - mnew);
                pv[ns][r] = p; rsum += p;
            }
            #pragma unroll
            for (int off = 8; off > 0; off >>= 1) rsum += __shfl_xor(rsum, off);
            l_run[r] = l_run[r] * alpha + rsum;
            m_run[r] = mnew;
            #pragma unroll
            for (int nc = 0; nc < 16; nc++) of[nc][r] *= alpha;
        }
        // ---- P: C/D layout -> LDS -> A layout (wave-private) ----
        #pragma unroll
        for (int ns = 0; ns < 4; ns++)
            #pragma unroll
            for (int r = 0; r < 4; r++)
                Ps[w][quad * 4 + r][ns * 16 + l16] = f2b(pv[ns][r]);
        // (compiler inserts in-wave lgkm wait for the dependent ds_read below)
        // ---- O += P * V^T ----
        #pragma unroll
        for (int ks2 = 0; ks2 < 2; ks2++) {
            s16x8 pa = *(const s16x8*)(&Ps[w][l16][ks2 * 32 + quad * 8]);
            #pragma unroll
            for (int nc = 0; nc < 16; nc++) {
                s16x8 bf = *(const s16x8*)(&Vs[(size_t)((nc * 2 + ks2) * 64 + lane) * 8]);
                of[nc] = __builtin_amdgcn_mfma_f32_16x16x32_bf16(pa, bf, of[nc], 0, 0, 0);
            }
        }
        __syncthreads();   // protect Ks/Vs from next iteration's staging writes
    }
    float inv[4];
    #pragma unroll
    for (int r = 0; r < 4; r++) inv[r] = 1.f / l_run[r];
    #pragma unroll
    for (int nc = 0; nc < 16; nc++)
        #pragma unroll
        for (int r = 0; r < 4; r++)
            OT[(size_t)(b * Ll + i0 + quad * 4 + r) * Cc + nc * 16 + l16] = f2b(of[nc][r] * inv[r]);
}

// ---------------- Kernel 6: projection + bias + residual -> out fp32 ----------------
__launch_bounds__(256, 1)
__global__ void k_proj(const u16* __restrict__ OT, const u16* __restrict__ Wp16,
                       const float* __restrict__ bp, const float* __restrict__ x,
                       float* __restrict__ out) {
    int ox = blockIdx.x, ly = blockIdx.y, b = blockIdx.z;
    int t = threadIdx.x, w = t >> 6, lane = t & 63;
    int l16 = lane & 15, quad = lane >> 4;
    int o0 = ox * 64, l0 = ly * 64;
    __shared__ u16 Os[64][264];
    {
        int row = t >> 2, chunk = t & 3;
        const u16* src = OT + (size_t)(b * Ll + l0 + row) * Cc + chunk * 64;
        u16* dst = &Os[row][chunk * 64];
        #pragma unroll
        for (int u = 0; u < 8; u++)
            *(uint4*)(dst + u * 8) = *(const uint4*)(src + u * 8);
    }
    s16x8 af[8];
    {
        const u16* wrow = Wp16 + (size_t)(o0 + w * 16 + l16) * Cc + quad * 8;
        #pragma unroll
        for (int ks = 0; ks < 8; ks++) af[ks] = *(const s16x8*)(wrow + ks * 32);
    }
    __syncthreads();
    f32x4 acc[4];
    #pragma unroll
    for (int ns = 0; ns < 4; ns++)
        #pragma unroll
        for (int r = 0; r < 4; r++) acc[ns][r] = 0.f;
    #pragma unroll
    for (int ks = 0; ks < 8; ks++) {
        #pragma unroll
        for (int ns = 0; ns < 4; ns++) {
            s16x8 bf = *(const s16x8*)(&Os[ns * 16 + l16][ks * 32 + quad * 8]);
            acc[ns] = __builtin_amdgcn_mfma_f32_16x16x32_bf16(af[ks], bf, acc[ns], 0, 0, 0);
        }
    }
    int ob = o0 + w * 16 + quad * 4;
    float bias[4];
    #pragma unroll
    for (int r = 0; r < 4; r++) bias[r] = bp[ob + r];
    #pragma unroll
    for (int ns = 0; ns < 4; ns++) {
        #pragma unroll
        for (int r = 0; r < 4; r++) {
            int o = ob + r;
            int l = l0 + ns * 16 + l16;
            size_t idx = (size_t)(b * Cc + o) * Ll + l;
            out[idx] = x[idx] + bias[r] + acc[ns][r];
        }
    }
}

// ---------------- launch ----------------
extern "C" void kernel_launch(void* const* d_in, const int* in_sizes, int n_in,
                              void* d_out, int out_size, void* d_ws, size_t ws_size,
                              hipStream_t stream) {
    const float* x     = (const float*)d_in[0];
    const float* gamma = (const float*)d_in[1];
    const float* beta  = (const float*)d_in[2];
    const float* wq    = (const float*)d_in[3];
    const float* bq    = (const float*)d_in[4];
    const float* wk    = (const float*)d_in[5];
    const float* bk    = (const float*)d_in[6];
    const float* wv    = (const float*)d_in[7];
    const float* bv    = (const float*)d_in[8];
    const float* wp    = (const float*)d_in[9];
    const float* bp    = (const float*)d_in[10];
    float* out = (float*)d_out;
    char* ws = (char*)d_ws;

    float* coefA   = (float*)(ws + 0);
    float* coefB   = (float*)(ws + 1024);
    float* biasQKV = (float*)(ws + 2048);
    u16*   Wqkv    = (u16*)(ws + 8192);
    u16*   Wp16    = (u16*)(ws + 401408);
    u16*   XT      = (u16*)(ws + 532480);
    u16*   QT      = (u16*)(ws + 8921088);
    u16*   KT      = (u16*)(ws + 17309696);
    u16*   V       = (u16*)(ws + 25698304);
    u16*   OT      = XT;

    k_stats<<<256, 256, 0, stream>>>(x, gamma, beta, coefA, coefB);
    k_fold<<<1024, 256, 0, stream>>>(wq, bq, wk, bk, wv, bv, wp, coefA, coefB,
                                     Wqkv, biasQKV, Wp16);
    k_transpose<<<dim3(64, 4, 4), 256, 0, stream>>>(x, XT);
    k_qkv<<<dim3(12, 64, 4), 256, 0, stream>>>(XT, Wqkv, biasQKV, QT, KT, V);
    k_attn<<<256, 256, 0, stream>>>(QT, KT, V, OT);
    k_proj<<<dim3(4, 64, 4), 256, 0, stream>>>(OT, Wp16, bp, x, out);
}

// Round 4
// 402.125 us; speedup vs baseline: 1.8257x; 1.2838x over previous
//
#include <hip/hip_runtime.h>
#include <math.h>

typedef unsigned short u16;
typedef unsigned int u32;
typedef short s16x8 __attribute__((ext_vector_type(8)));   // 8 bf16 (4 VGPRs)
typedef float f32x4 __attribute__((ext_vector_type(4)));   // 4 fp32 acc

static constexpr int Cc = 256;
static constexpr int Ll = 4096;
static constexpr int Bb = 4;

__device__ __forceinline__ u16 f2b(float f) {
    union { float f; unsigned u; } v; v.f = f;
    unsigned r = v.u + 0x7FFF + ((v.u >> 16) & 1);   // RNE
    return (u16)(r >> 16);
}

// async 16B global->LDS (lds dest = wave-uniform base + lane*16)
__device__ __forceinline__ void gload_lds16(const u16* g, u16* l) {
    __builtin_amdgcn_global_load_lds(
        (const __attribute__((address_space(1))) u32*)g,
        (__attribute__((address_space(3))) u32*)l, 16, 0, 0);
}

// ---------------- Kernel 1: BN stats -> folded affine coefs ----------------
__global__ void k_stats(const float* __restrict__ x, const float* __restrict__ gamma,
                        const float* __restrict__ beta, float* __restrict__ coefA,
                        float* __restrict__ coefB) {
    int c = blockIdx.x, t = threadIdx.x;
    float s = 0.f, s2 = 0.f;
    for (int idx = t; idx < Bb * Ll; idx += 256) {
        int b = idx >> 12, l = idx & (Ll - 1);
        float v = x[(size_t)(b * Cc + c) * Ll + l];
        s += v; s2 += v * v;
    }
    __shared__ float rs[256], rs2[256];
    rs[t] = s; rs2[t] = s2; __syncthreads();
    for (int off = 128; off > 0; off >>= 1) {
        if (t < off) { rs[t] += rs[t + off]; rs2[t] += rs2[t + off]; }
        __syncthreads();
    }
    if (t == 0) {
        float mean = rs[0] / (Bb * Ll);
        float var  = rs2[0] / (Bb * Ll) - mean * mean;   // biased, as torch BN
        float rstd = rsqrtf(var + 1e-5f);
        float a = gamma[c] * rstd;
        coefA[c] = a;
        coefB[c] = beta[c] - mean * a;
    }
}

// ---------------- Kernel 2: fold BN into weights, convert bf16 ----------------
__global__ void k_fold(const float* __restrict__ wq, const float* __restrict__ bq,
                       const float* __restrict__ wk, const float* __restrict__ bk,
                       const float* __restrict__ wv, const float* __restrict__ bv,
                       const float* __restrict__ wp,
                       const float* __restrict__ coefA, const float* __restrict__ coefB,
                       u16* __restrict__ Wqkv, float* __restrict__ biasQKV,
                       u16* __restrict__ Wp16) {
    int m = blockIdx.x, t = threadIdx.x;
    if (m >= 768) {
        int row = m - 768;
        Wp16[row * Cc + t] = f2b(wp[row * Cc + t]);
        return;
    }
    int type = m >> 8, row = m & 255;
    const float* W  = (type == 0) ? wq : (type == 1) ? wk : wv;
    const float* bs = (type == 0) ? bq : (type == 1) ? bk : bv;
    float wval = W[row * Cc + t];
    float s2 = (type == 0) ? 0.09016844005556021f : 1.0f;  // (1/sqrt(C)) * log2(e)
    Wqkv[m * Cc + t] = f2b(wval * coefA[t] * s2);
    __shared__ float rs[256];
    rs[t] = wval * coefB[t];
    __syncthreads();
    for (int off = 128; off > 0; off >>= 1) {
        if (t < off) rs[t] += rs[t + off];
        __syncthreads();
    }
    if (t == 0) biasQKV[m] = (bs[row] + rs[0]) * s2;
}

// ---------------- Kernel 3: x [B][C][L] fp32 -> XT [B][L][C] bf16 ----------------
__global__ void k_transpose(const float* __restrict__ x, u16* __restrict__ XT) {
    int lt = blockIdx.x, ct = blockIdx.y, b = blockIdx.z, t = threadIdx.x;
    int l0 = lt * 64, c0 = ct * 64;
    __shared__ u16 tile[64][65];
    int ll = t & 63, cb = t >> 6;
    #pragma unroll
    for (int rep = 0; rep < 16; rep++) {
        int cl = cb * 16 + rep;
        tile[cl][ll] = f2b(x[(size_t)(b * Cc + c0 + cl) * Ll + l0 + ll]);
    }
    __syncthreads();
    int cl2 = t & 63, lb = t >> 6;
    #pragma unroll
    for (int rep = 0; rep < 16; rep++) {
        int ll2 = lb * 16 + rep;
        XT[(size_t)(b * Ll + l0 + ll2) * Cc + c0 + cl2] = tile[cl2][ll2];
    }
}

// ---------------- Kernel 4: QKV GEMM -> QT,KT [B][L][C], V [B][C][L] (all bf16) --
__launch_bounds__(256, 1)
__global__ void k_qkv(const u16* __restrict__ XT, const u16* __restrict__ Wqkv,
                      const float* __restrict__ biasQKV,
                      u16* __restrict__ QT, u16* __restrict__ KT, u16* __restrict__ V) {
    int ox = blockIdx.x, ly = blockIdx.y, b = blockIdx.z;
    int t = threadIdx.x, w = t >> 6, lane = t & 63;
    int l16 = lane & 15, quad = lane >> 4;
    int o0 = ox * 64, l0 = ly * 64;
    __shared__ u16 Xs[64][264];
    {
        int row = t >> 2, chunk = t & 3;
        const u16* src = XT + (size_t)(b * Ll + l0 + row) * Cc + chunk * 64;
        u16* dst = &Xs[row][chunk * 64];
        #pragma unroll
        for (int u = 0; u < 8; u++)
            *(uint4*)(dst + u * 8) = *(const uint4*)(src + u * 8);
    }
    s16x8 af[8];
    {
        const u16* wrow = Wqkv + (size_t)(o0 + w * 16 + l16) * Cc + quad * 8;
        #pragma unroll
        for (int ks = 0; ks < 8; ks++) af[ks] = *(const s16x8*)(wrow + ks * 32);
    }
    __syncthreads();
    f32x4 acc[4];
    #pragma unroll
    for (int ns = 0; ns < 4; ns++)
        #pragma unroll
        for (int r = 0; r < 4; r++) acc[ns][r] = 0.f;
    #pragma unroll
    for (int ks = 0; ks < 8; ks++) {
        #pragma unroll
        for (int ns = 0; ns < 4; ns++) {
            s16x8 bf = *(const s16x8*)(&Xs[ns * 16 + l16][ks * 32 + quad * 8]);
            acc[ns] = __builtin_amdgcn_mfma_f32_16x16x32_bf16(af[ks], bf, acc[ns], 0, 0, 0);
        }
    }
    int obase = o0 + w * 16 + quad * 4;
    float bias[4];
    #pragma unroll
    for (int r = 0; r < 4; r++) bias[r] = biasQKV[obase + r];
    #pragma unroll
    for (int ns = 0; ns < 4; ns++) {
        int l = l0 + ns * 16 + l16;
        if (ox < 8) {
            u16* dstbase = (ox < 4) ? QT : KT;
            int oo = obase - ((ox < 4) ? 0 : 256);
            ushort4 pk;
            pk.x = f2b(acc[ns][0] + bias[0]);
            pk.y = f2b(acc[ns][1] + bias[1]);
            pk.z = f2b(acc[ns][2] + bias[2]);
            pk.w = f2b(acc[ns][3] + bias[3]);
            *(ushort4*)(dstbase + (size_t)(b * Ll + l) * Cc + oo) = pk;
        } else {
            #pragma unroll
            for (int r = 0; r < 4; r++) {
                int o = obase + r - 512;
                V[(size_t)(b * Cc + o) * Ll + l] = f2b(acc[ns][r] + bias[r]);
            }
        }
    }
}

// ---------------- Kernel 5: flash attention -> OT [B][L][C] bf16 ----------------
// 256 blocks (b x 64 i-tiles), 4 waves x 16 rows.
// K/V tiles double-buffered in LDS, filled with async global_load_lds (no VGPR
// round-trip, no spills). Fragment-permuted layout: staging writes and MFMA
// fragment reads are both lane-linear 16B. One barrier per iteration.
__launch_bounds__(256, 1)
__global__ void k_attn(const u16* __restrict__ QT, const u16* __restrict__ KT,
                       const u16* __restrict__ V, u16* __restrict__ OT) {
    int id = blockIdx.x;
    int xcd = id & 7, local = id >> 3;
    int b = xcd >> 1;
    int itile = local * 2 + (xcd & 1);
    int t = threadIdx.x, w = t >> 6, lane = t & 63;
    int l16 = lane & 15, quad = lane >> 4;
    int i0 = itile * 64 + w * 16;

    __shared__ u16 Ks[2][16384];    // 2 x 32KB fragment-permuted K tiles
    __shared__ u16 Vs[2][16384];    // 2 x 32KB fragment-permuted V tiles
    __shared__ u16 Ps[4][16][72];   // per-wave P round-trip

    // Q fragments (A-layout) in registers
    s16x8 qf[8];
    {
        const u16* qrow = QT + (size_t)(b * Ll + i0 + l16) * Cc + quad * 8;
        #pragma unroll
        for (int ks = 0; ks < 8; ks++) qf[ks] = *(const s16x8*)(qrow + ks * 32);
    }

    // Per-round global source pointers (lane-dependent), advanced each iter.
    //  round R covers fragment g = R*4+w; LDS chunk index = g*64+lane.
    const u16* Kb = KT + (size_t)b * Ll * Cc;
    const u16* Vb = V + (size_t)b * Cc * Ll;
    const u16* kptr[8];
    const u16* vptr[8];
    #pragma unroll
    for (int R = 0; R < 8; R++) {
        int g = R * 4 + w;
        int ns = g >> 3, ks = g & 7;
        kptr[R] = Kb + (size_t)(ns * 16 + l16) * Cc + ks * 32 + quad * 8;
        int nc = g >> 1, ks2 = g & 1;
        vptr[R] = Vb + (size_t)(nc * 16 + l16) * Ll + ks2 * 32 + quad * 8;
    }

    // prologue: issue async loads for jt=0 into buffer 0
    #pragma unroll
    for (int R = 0; R < 8; R++) {
        u16* kl = &Ks[0][(size_t)(R * 256 + w * 64) * 8];
        u16* vl = &Vs[0][(size_t)(R * 256 + w * 64) * 8];
        gload_lds16(kptr[R], kl);
        gload_lds16(vptr[R], vl);
        kptr[R] += 64 * Cc;   // next j-tile of K rows
        vptr[R] += 64;        // next 64 columns of V
    }

    f32x4 of[16];
    #pragma unroll
    for (int nc = 0; nc < 16; nc++)
        #pragma unroll
        for (int r = 0; r < 4; r++) of[nc][r] = 0.f;
    float m_run[4], l_run[4];
    #pragma unroll
    for (int r = 0; r < 4; r++) { m_run[r] = -INFINITY; l_run[r] = 0.f; }

    for (int jt = 0; jt < 64; jt++) {
        int buf = jt & 1;
        // drains vmcnt (compiler) -> buf complete on all waves; prev reads done
        __syncthreads();
        // issue next tile's async loads into the other buffer
        if (jt < 63) {
            #pragma unroll
            for (int R = 0; R < 8; R++) {
                u16* kl = &Ks[buf ^ 1][(size_t)(R * 256 + w * 64) * 8];
                u16* vl = &Vs[buf ^ 1][(size_t)(R * 256 + w * 64) * 8];
                gload_lds16(kptr[R], kl);
                gload_lds16(vptr[R], vl);
                kptr[R] += 64 * Cc;
                vptr[R] += 64;
            }
        }
        // ---- S = Q K^T (scale*log2e folded into Wq) ----
        f32x4 sf[4];
        #pragma unroll
        for (int ns = 0; ns < 4; ns++)
            #pragma unroll
            for (int r = 0; r < 4; r++) sf[ns][r] = 0.f;
        #pragma unroll
        for (int ks = 0; ks < 8; ks++) {
            #pragma unroll
            for (int ns = 0; ns < 4; ns++) {
                s16x8 bf = *(const s16x8*)(&Ks[buf][(size_t)((ns * 8 + ks) * 64 + lane) * 8]);
                sf[ns] = __builtin_amdgcn_mfma_f32_16x16x32_bf16(qf[ks], bf, sf[ns], 0, 0, 0);
            }
        }
        // ---- online softmax ----
        float pv[4][4];
        #pragma unroll
        for (int r = 0; r < 4; r++) {
            float tm = fmaxf(fmaxf(sf[0][r], sf[1][r]), fmaxf(sf[2][r], sf[3][r]));
            #pragma unroll
            for (int off = 8; off > 0; off >>= 1) tm = fmaxf(tm, __shfl_xor(tm, off));
            float mnew = fmaxf(m_run[r], tm);
            float alpha = exp2f(m_run[r] - mnew);
            float rsum = 0.f;
            #pragma unroll
            for (int ns = 0; ns < 4; ns++) {
                float p = exp2f(sf[ns][r] - mnew);
                pv[ns][r] = p; rsum += p;
            }
            #pragma unroll
            for (int off = 8; off > 0; off >>= 1) rsum += __shfl_xor(rsum, off);
            l_run[r] = l_run[r] * alpha + rsum;
            m_run[r] = mnew;
            #pragma unroll
            for (int nc = 0; nc < 16; nc++) of[nc][r] *= alpha;
        }
        // ---- P: C/D layout -> LDS -> A layout (wave-private, in-wave DS order) ----
        #pragma unroll
        for (int ns = 0; ns < 4; ns++)
            #pragma unroll
            for (int r = 0; r < 4; r++)
                Ps[w][quad * 4 + r][ns * 16 + l16] = f2b(pv[ns][r]);
        // ---- O += P * V^T ----
        #pragma unroll
        for (int ks2 = 0; ks2 < 2; ks2++) {
            s16x8 pa = *(const s16x8*)(&Ps[w][l16][ks2 * 32 + quad * 8]);
            #pragma unroll
            for (int nc = 0; nc < 16; nc++) {
                s16x8 bf = *(const s16x8*)(&Vs[buf][(size_t)((nc * 2 + ks2) * 64 + lane) * 8]);
                of[nc] = __builtin_amdgcn_mfma_f32_16x16x32_bf16(pa, bf, of[nc], 0, 0, 0);
            }
        }
    }
    float inv[4];
    #pragma unroll
    for (int r = 0; r < 4; r++) inv[r] = 1.f / l_run[r];
    #pragma unroll
    for (int nc = 0; nc < 16; nc++)
        #pragma unroll
        for (int r = 0; r < 4; r++)
            OT[(size_t)(b * Ll + i0 + quad * 4 + r) * Cc + nc * 16 + l16] = f2b(of[nc][r] * inv[r]);
}

// ---------------- Kernel 6: projection + bias + residual -> out fp32 ----------------
__launch_bounds__(256, 1)
__global__ void k_proj(const u16* __restrict__ OT, const u16* __restrict__ Wp16,
                       const float* __restrict__ bp, const float* __restrict__ x,
                       float* __restrict__ out) {
    int ox = blockIdx.x, ly = blockIdx.y, b = blockIdx.z;
    int t = threadIdx.x, w = t >> 6, lane = t & 63;
    int l16 = lane & 15, quad = lane >> 4;
    int o0 = ox * 64, l0 = ly * 64;
    __shared__ u16 Os[64][264];
    {
        int row = t >> 2, chunk = t & 3;
        const u16* src = OT + (size_t)(b * Ll + l0 + row) * Cc + chunk * 64;
        u16* dst = &Os[row][chunk * 64];
        #pragma unroll
        for (int u = 0; u < 8; u++)
            *(uint4*)(dst + u * 8) = *(const uint4*)(src + u * 8);
    }
    s16x8 af[8];
    {
        const u16* wrow = Wp16 + (size_t)(o0 + w * 16 + l16) * Cc + quad * 8;
        #pragma unroll
        for (int ks = 0; ks < 8; ks++) af[ks] = *(const s16x8*)(wrow + ks * 32);
    }
    __syncthreads();
    f32x4 acc[4];
    #pragma unroll
    for (int ns = 0; ns < 4; ns++)
        #pragma unroll
        for (int r = 0; r < 4; r++) acc[ns][r] = 0.f;
    #pragma unroll
    for (int ks = 0; ks < 8; ks++) {
        #pragma unroll
        for (int ns = 0; ns < 4; ns++) {
            s16x8 bf = *(const s16x8*)(&Os[ns * 16 + l16][ks * 32 + quad * 8]);
            acc[ns] = __builtin_amdgcn_mfma_f32_16x16x32_bf16(af[ks], bf, acc[ns], 0, 0, 0);
        }
    }
    int ob = o0 + w * 16 + quad * 4;
    float bias[4];
    #pragma unroll
    for (int r = 0; r < 4; r++) bias[r] = bp[ob + r];
    #pragma unroll
    for (int ns = 0; ns < 4; ns++) {
        #pragma unroll
        for (int r = 0; r < 4; r++) {
            int o = ob + r;
            int l = l0 + ns * 16 + l16;
            size_t idx = (size_t)(b * Cc + o) * Ll + l;
            out[idx] = x[idx] + bias[r] + acc[ns][r];
        }
    }
}

// ---------------- launch ----------------
extern "C" void kernel_launch(void* const* d_in, const int* in_sizes, int n_in,
                              void* d_out, int out_size, void* d_ws, size_t ws_size,
                              hipStream_t stream) {
    const float* x     = (const float*)d_in[0];
    const float* gamma = (const float*)d_in[1];
    const float* beta  = (const float*)d_in[2];
    const float* wq    = (const float*)d_in[3];
    const float* bq    = (const float*)d_in[4];
    const float* wk    = (const float*)d_in[5];
    const float* bk    = (const float*)d_in[6];
    const float* wv    = (const float*)d_in[7];
    const float* bv    = (const float*)d_in[8];
    const float* wp    = (const float*)d_in[9];
    const float* bp    = (const float*)d_in[10];
    float* out = (float*)d_out;
    char* ws = (char*)d_ws;

    float* coefA   = (float*)(ws + 0);
    float* coefB   = (float*)(ws + 1024);
    float* biasQKV = (float*)(ws + 2048);
    u16*   Wqkv    = (u16*)(ws + 8192);
    u16*   Wp16    = (u16*)(ws + 401408);
    u16*   XT      = (u16*)(ws + 532480);
    u16*   QT      = (u16*)(ws + 8921088);
    u16*   KT      = (u16*)(ws + 17309696);
    u16*   V       = (u16*)(ws + 25698304);
    u16*   OT      = XT;

    k_stats<<<256, 256, 0, stream>>>(x, gamma, beta, coefA, coefB);
    k_fold<<<1024, 256, 0, stream>>>(wq, bq, wk, bk, wv, bv, wp, coefA, coefB,
                                     Wqkv, biasQKV, Wp16);
    k_transpose<<<dim3(64, 4, 4), 256, 0, stream>>>(x, XT);
    k_qkv<<<dim3(12, 64, 4), 256, 0, stream>>>(XT, Wqkv, biasQKV, QT, KT, V);
    k_attn<<<256, 256, 0, stream>>>(QT, KT, V, OT);
    k_proj<<<dim3(4, 64, 4), 256, 0, stream>>>(OT, Wp16, bp, x, out);
}

// Round 5
// 386.653 us; speedup vs baseline: 1.8988x; 1.0400x over previous
//
#include <hip/hip_runtime.h>
#include <math.h>

typedef unsigned short u16;
typedef unsigned int u32;
typedef short s16x8 __attribute__((ext_vector_type(8)));   // 8 bf16 (4 VGPRs)
typedef float f32x4 __attribute__((ext_vector_type(4)));   // 4 fp32 acc

static constexpr int Cc = 256;
static constexpr int Ll = 4096;
static constexpr int Bb = 4;

__device__ __forceinline__ u16 f2b(float f) {
    union { float f; unsigned u; } v; v.f = f;
    unsigned r = v.u + 0x7FFF + ((v.u >> 16) & 1);   // RNE
    return (u16)(r >> 16);
}

// async 16B global->LDS (lds dest = wave-uniform base + lane*16)
__device__ __forceinline__ void gload_lds16(const u16* g, u16* l) {
    __builtin_amdgcn_global_load_lds(
        (const __attribute__((address_space(1))) u32*)g,
        (__attribute__((address_space(3))) u32*)l, 16, 0, 0);
}

// ---------------- Kernel 1: BN stats -> folded affine coefs ----------------
__global__ void k_stats(const float* __restrict__ x, const float* __restrict__ gamma,
                        const float* __restrict__ beta, float* __restrict__ coefA,
                        float* __restrict__ coefB) {
    int c = blockIdx.x, t = threadIdx.x;
    float s = 0.f, s2 = 0.f;
    for (int idx = t; idx < Bb * Ll; idx += 256) {
        int b = idx >> 12, l = idx & (Ll - 1);
        float v = x[(size_t)(b * Cc + c) * Ll + l];
        s += v; s2 += v * v;
    }
    __shared__ float rs[256], rs2[256];
    rs[t] = s; rs2[t] = s2; __syncthreads();
    for (int off = 128; off > 0; off >>= 1) {
        if (t < off) { rs[t] += rs[t + off]; rs2[t] += rs2[t + off]; }
        __syncthreads();
    }
    if (t == 0) {
        float mean = rs[0] / (Bb * Ll);
        float var  = rs2[0] / (Bb * Ll) - mean * mean;   // biased, as torch BN
        float rstd = rsqrtf(var + 1e-5f);
        float a = gamma[c] * rstd;
        coefA[c] = a;
        coefB[c] = beta[c] - mean * a;
    }
}

// ---------------- Kernel 2: fold BN into weights, convert bf16 ----------------
__global__ void k_fold(const float* __restrict__ wq, const float* __restrict__ bq,
                       const float* __restrict__ wk, const float* __restrict__ bk,
                       const float* __restrict__ wv, const float* __restrict__ bv,
                       const float* __restrict__ wp,
                       const float* __restrict__ coefA, const float* __restrict__ coefB,
                       u16* __restrict__ Wqkv, float* __restrict__ biasQKV,
                       u16* __restrict__ Wp16) {
    int m = blockIdx.x, t = threadIdx.x;
    if (m >= 768) {
        int row = m - 768;
        Wp16[row * Cc + t] = f2b(wp[row * Cc + t]);
        return;
    }
    int type = m >> 8, row = m & 255;
    const float* W  = (type == 0) ? wq : (type == 1) ? wk : wv;
    const float* bs = (type == 0) ? bq : (type == 1) ? bk : bv;
    float wval = W[row * Cc + t];
    float s2 = (type == 0) ? 0.09016844005556021f : 1.0f;  // (1/sqrt(C)) * log2(e)
    Wqkv[m * Cc + t] = f2b(wval * coefA[t] * s2);
    __shared__ float rs[256];
    rs[t] = wval * coefB[t];
    __syncthreads();
    for (int off = 128; off > 0; off >>= 1) {
        if (t < off) rs[t] += rs[t + off];
        __syncthreads();
    }
    if (t == 0) biasQKV[m] = (bs[row] + rs[0]) * s2;
}

// ---------------- Kernel 3: x [B][C][L] fp32 -> XT [B][L][C] bf16 ----------------
__global__ void k_transpose(const float* __restrict__ x, u16* __restrict__ XT) {
    int lt = blockIdx.x, ct = blockIdx.y, b = blockIdx.z, t = threadIdx.x;
    int l0 = lt * 64, c0 = ct * 64;
    __shared__ u16 tile[64][65];
    int ll = t & 63, cb = t >> 6;
    #pragma unroll
    for (int rep = 0; rep < 16; rep++) {
        int cl = cb * 16 + rep;
        tile[cl][ll] = f2b(x[(size_t)(b * Cc + c0 + cl) * Ll + l0 + ll]);
    }
    __syncthreads();
    int cl2 = t & 63, lb = t >> 6;
    #pragma unroll
    for (int rep = 0; rep < 16; rep++) {
        int ll2 = lb * 16 + rep;
        XT[(size_t)(b * Ll + l0 + ll2) * Cc + c0 + cl2] = tile[cl2][ll2];
    }
}

// ---------------- Kernel 4: QKV GEMM -> QT,KT [B][L][C], V [B][C][L] (all bf16) --
__launch_bounds__(256, 1)
__global__ void k_qkv(const u16* __restrict__ XT, const u16* __restrict__ Wqkv,
                      const float* __restrict__ biasQKV,
                      u16* __restrict__ QT, u16* __restrict__ KT, u16* __restrict__ V) {
    int ox = blockIdx.x, ly = blockIdx.y, b = blockIdx.z;
    int t = threadIdx.x, w = t >> 6, lane = t & 63;
    int l16 = lane & 15, quad = lane >> 4;
    int o0 = ox * 64, l0 = ly * 64;
    __shared__ u16 Xs[64][264];
    {
        int row = t >> 2, chunk = t & 3;
        const u16* src = XT + (size_t)(b * Ll + l0 + row) * Cc + chunk * 64;
        u16* dst = &Xs[row][chunk * 64];
        #pragma unroll
        for (int u = 0; u < 8; u++)
            *(uint4*)(dst + u * 8) = *(const uint4*)(src + u * 8);
    }
    s16x8 af[8];
    {
        const u16* wrow = Wqkv + (size_t)(o0 + w * 16 + l16) * Cc + quad * 8;
        #pragma unroll
        for (int ks = 0; ks < 8; ks++) af[ks] = *(const s16x8*)(wrow + ks * 32);
    }
    __syncthreads();
    f32x4 acc[4];
    #pragma unroll
    for (int ns = 0; ns < 4; ns++)
        #pragma unroll
        for (int r = 0; r < 4; r++) acc[ns][r] = 0.f;
    #pragma unroll
    for (int ks = 0; ks < 8; ks++) {
        #pragma unroll
        for (int ns = 0; ns < 4; ns++) {
            s16x8 bf = *(const s16x8*)(&Xs[ns * 16 + l16][ks * 32 + quad * 8]);
            acc[ns] = __builtin_amdgcn_mfma_f32_16x16x32_bf16(af[ks], bf, acc[ns], 0, 0, 0);
        }
    }
    int obase = o0 + w * 16 + quad * 4;
    float bias[4];
    #pragma unroll
    for (int r = 0; r < 4; r++) bias[r] = biasQKV[obase + r];
    #pragma unroll
    for (int ns = 0; ns < 4; ns++) {
        int l = l0 + ns * 16 + l16;
        if (ox < 8) {
            u16* dstbase = (ox < 4) ? QT : KT;
            int oo = obase - ((ox < 4) ? 0 : 256);
            ushort4 pk;
            pk.x = f2b(acc[ns][0] + bias[0]);
            pk.y = f2b(acc[ns][1] + bias[1]);
            pk.z = f2b(acc[ns][2] + bias[2]);
            pk.w = f2b(acc[ns][3] + bias[3]);
            *(ushort4*)(dstbase + (size_t)(b * Ll + l) * Cc + oo) = pk;
        } else {
            #pragma unroll
            for (int r = 0; r < 4; r++) {
                int o = obase + r - 512;
                V[(size_t)(b * Cc + o) * Ll + l] = f2b(acc[ns][r] + bias[r]);
            }
        }
    }
}

// ---------------- Kernel 5: flash attention -> OT [B][L][C] bf16 ----------------
// 256 blocks (b x 64 i-tiles), 4 waves x 16 rows. Two-phase pipeline:
//   Ka (32KB) holds K(jt), Vb (32KB) holds V(jt); async global_load_lds
//   prefetch one PHASE ahead; 2 barriers/iter; LDS total 74.75KB -> 2 blocks/CU
//   so barrier stalls of one block are filled by the other block's waves.
__launch_bounds__(256, 2)
__global__ void k_attn(const u16* __restrict__ QT, const u16* __restrict__ KT,
                       const u16* __restrict__ V, u16* __restrict__ OT) {
    int id = blockIdx.x;
    int xcd = id & 7, local = id >> 3;
    int b = xcd >> 1;
    int itile = local * 2 + (xcd & 1);
    int t = threadIdx.x, w = t >> 6, lane = t & 63;
    int l16 = lane & 15, quad = lane >> 4;
    int i0 = itile * 64 + w * 16;

    __shared__ u16 Ka[16384];       // 32KB fragment-permuted K tile (phase A)
    __shared__ u16 Vbuf[16384];     // 32KB fragment-permuted V tile (phase B)
    __shared__ u16 Ps[4][16][72];   // per-wave P round-trip (9.2KB)

    // Q fragments (A-layout) in registers
    s16x8 qf[8];
    {
        const u16* qrow = QT + (size_t)(b * Ll + i0 + l16) * Cc + quad * 8;
        #pragma unroll
        for (int ks = 0; ks < 8; ks++) qf[ks] = *(const s16x8*)(qrow + ks * 32);
    }

    // Per-round global source pointers; fragment g = R*4+w at LDS chunk g*64+lane.
    const u16* Kb = KT + (size_t)b * Ll * Cc;
    const u16* Vg = V + (size_t)b * Cc * Ll;
    const u16* kptr[8];
    const u16* vptr[8];
    #pragma unroll
    for (int R = 0; R < 8; R++) {
        int g = R * 4 + w;
        int ns = g >> 3, ks = g & 7;
        kptr[R] = Kb + (size_t)(ns * 16 + l16) * Cc + ks * 32 + quad * 8;
        int nc = g >> 1, ks2 = g & 1;
        vptr[R] = Vg + (size_t)(nc * 16 + l16) * Ll + ks2 * 32 + quad * 8;
    }

    // prologue: issue K(0) and V(0)
    #pragma unroll
    for (int R = 0; R < 8; R++) {
        gload_lds16(kptr[R], &Ka[(size_t)(R * 256 + w * 64) * 8]);
        kptr[R] += 64 * Cc;
    }
    #pragma unroll
    for (int R = 0; R < 8; R++) {
        gload_lds16(vptr[R], &Vbuf[(size_t)(R * 256 + w * 64) * 8]);
        vptr[R] += 64;
    }

    f32x4 of[16];
    #pragma unroll
    for (int nc = 0; nc < 16; nc++)
        #pragma unroll
        for (int r = 0; r < 4; r++) of[nc][r] = 0.f;
    float m_run[4], l_run[4];
    #pragma unroll
    for (int r = 0; r < 4; r++) { m_run[r] = -INFINITY; l_run[r] = 0.f; }

    __syncthreads();   // P0: drains K(0), V(0)

    for (int jt = 0; jt < 64; jt++) {
        // ---- phase A: S = Q K^T from Ka (scale*log2e folded into Wq) ----
        f32x4 sf[4];
        #pragma unroll
        for (int ns = 0; ns < 4; ns++)
            #pragma unroll
            for (int r = 0; r < 4; r++) sf[ns][r] = 0.f;
        #pragma unroll
        for (int ks = 0; ks < 8; ks++) {
            #pragma unroll
            for (int ns = 0; ns < 4; ns++) {
                s16x8 bf = *(const s16x8*)(&Ka[(size_t)((ns * 8 + ks) * 64 + lane) * 8]);
                sf[ns] = __builtin_amdgcn_mfma_f32_16x16x32_bf16(qf[ks], bf, sf[ns], 0, 0, 0);
            }
        }
        __syncthreads();   // M: Ka reads done on all waves; drains V(jt) loads
        // issue K(jt+1) into Ka (in flight during phase B)
        if (jt < 63) {
            #pragma unroll
            for (int R = 0; R < 8; R++) {
                gload_lds16(kptr[R], &Ka[(size_t)(R * 256 + w * 64) * 8]);
                kptr[R] += 64 * Cc;
            }
        }
        // ---- online softmax ----
        float pv[4][4];
        #pragma unroll
        for (int r = 0; r < 4; r++) {
            float tm = fmaxf(fmaxf(sf[0][r], sf[1][r]), fmaxf(sf[2][r], sf[3][r]));
            #pragma unroll
            for (int off = 8; off > 0; off >>= 1) tm = fmaxf(tm, __shfl_xor(tm, off));
            float mnew = fmaxf(m_run[r], tm);
            float alpha = exp2f(m_run[r] - mnew);
            float rsum = 0.f;
            #pragma unroll
            for (int ns = 0; ns < 4; ns++) {
                float p = exp2f(sf[ns][r] - mnew);
                pv[ns][r] = p; rsum += p;
            }
            #pragma unroll
            for (int off = 8; off > 0; off >>= 1) rsum += __shfl_xor(rsum, off);
            l_run[r] = l_run[r] * alpha + rsum;
            m_run[r] = mnew;
            #pragma unroll
            for (int nc = 0; nc < 16; nc++) of[nc][r] *= alpha;
        }
        // ---- P: C/D layout -> LDS -> A layout (wave-private, in-wave DS order) ----
        #pragma unroll
        for (int ns = 0; ns < 4; ns++)
            #pragma unroll
            for (int r = 0; r < 4; r++)
                Ps[w][quad * 4 + r][ns * 16 + l16] = f2b(pv[ns][r]);
        // ---- phase B: O += P * V^T from Vbuf ----
        #pragma unroll
        for (int ks2 = 0; ks2 < 2; ks2++) {
            s16x8 pa = *(const s16x8*)(&Ps[w][l16][ks2 * 32 + quad * 8]);
            #pragma unroll
            for (int nc = 0; nc < 16; nc++) {
                s16x8 bf = *(const s16x8*)(&Vbuf[(size_t)((nc * 2 + ks2) * 64 + lane) * 8]);
                of[nc] = __builtin_amdgcn_mfma_f32_16x16x32_bf16(pa, bf, of[nc], 0, 0, 0);
            }
        }
        __syncthreads();   // B: Vbuf reads done on all waves; drains K(jt+1) loads
        // issue V(jt+1) into Vbuf (in flight during next phase A)
        if (jt < 63) {
            #pragma unroll
            for (int R = 0; R < 8; R++) {
                gload_lds16(vptr[R], &Vbuf[(size_t)(R * 256 + w * 64) * 8]);
                vptr[R] += 64;
            }
        }
    }
    float inv[4];
    #pragma unroll
    for (int r = 0; r < 4; r++) inv[r] = 1.f / l_run[r];
    #pragma unroll
    for (int nc = 0; nc < 16; nc++)
        #pragma unroll
        for (int r = 0; r < 4; r++)
            OT[(size_t)(b * Ll + i0 + quad * 4 + r) * Cc + nc * 16 + l16] = f2b(of[nc][r] * inv[r]);
}

// ---------------- Kernel 6: projection + bias + residual -> out fp32 ----------------
__launch_bounds__(256, 1)
__global__ void k_proj(const u16* __restrict__ OT, const u16* __restrict__ Wp16,
                       const float* __restrict__ bp, const float* __restrict__ x,
                       float* __restrict__ out) {
    int ox = blockIdx.x, ly = blockIdx.y, b = blockIdx.z;
    int t = threadIdx.x, w = t >> 6, lane = t & 63;
    int l16 = lane & 15, quad = lane >> 4;
    int o0 = ox * 64, l0 = ly * 64;
    __shared__ u16 Os[64][264];
    {
        int row = t >> 2, chunk = t & 3;
        const u16* src = OT + (size_t)(b * Ll + l0 + row) * Cc + chunk * 64;
        u16* dst = &Os[row][chunk * 64];
        #pragma unroll
        for (int u = 0; u < 8; u++)
            *(uint4*)(dst + u * 8) = *(const uint4*)(src + u * 8);
    }
    s16x8 af[8];
    {
        const u16* wrow = Wp16 + (size_t)(o0 + w * 16 + l16) * Cc + quad * 8;
        #pragma unroll
        for (int ks = 0; ks < 8; ks++) af[ks] = *(const s16x8*)(wrow + ks * 32);
    }
    __syncthreads();
    f32x4 acc[4];
    #pragma unroll
    for (int ns = 0; ns < 4; ns++)
        #pragma unroll
        for (int r = 0; r < 4; r++) acc[ns][r] = 0.f;
    #pragma unroll
    for (int ks = 0; ks < 8; ks++) {
        #pragma unroll
        for (int ns = 0; ns < 4; ns++) {
            s16x8 bf = *(const s16x8*)(&Os[ns * 16 + l16][ks * 32 + quad * 8]);
            acc[ns] = __builtin_amdgcn_mfma_f32_16x16x32_bf16(af[ks], bf, acc[ns], 0, 0, 0);
        }
    }
    int ob = o0 + w * 16 + quad * 4;
    float bias[4];
    #pragma unroll
    for (int r = 0; r < 4; r++) bias[r] = bp[ob + r];
    #pragma unroll
    for (int ns = 0; ns < 4; ns++) {
        #pragma unroll
        for (int r = 0; r < 4; r++) {
            int o = ob + r;
            int l = l0 + ns * 16 + l16;
            size_t idx = (size_t)(b * Cc + o) * Ll + l;
            out[idx] = x[idx] + bias[r] + acc[ns][r];
        }
    }
}

// ---------------- launch ----------------
extern "C" void kernel_launch(void* const* d_in, const int* in_sizes, int n_in,
                              void* d_out, int out_size, void* d_ws, size_t ws_size,
                              hipStream_t stream) {
    const float* x     = (const float*)d_in[0];
    const float* gamma = (const float*)d_in[1];
    const float* beta  = (const float*)d_in[2];
    const float* wq    = (const float*)d_in[3];
    const float* bq    = (const float*)d_in[4];
    const float* wk    = (const float*)d_in[5];
    const float* bk    = (const float*)d_in[6];
    const float* wv    = (const float*)d_in[7];
    const float* bv    = (const float*)d_in[8];
    const float* wp    = (const float*)d_in[9];
    const float* bp    = (const float*)d_in[10];
    float* out = (float*)d_out;
    char* ws = (char*)d_ws;

    float* coefA   = (float*)(ws + 0);
    float* coefB   = (float*)(ws + 1024);
    float* biasQKV = (float*)(ws + 2048);
    u16*   Wqkv    = (u16*)(ws + 8192);
    u16*   Wp16    = (u16*)(ws + 401408);
    u16*   XT      = (u16*)(ws + 532480);
    u16*   QT      = (u16*)(ws + 8921088);
    u16*   KT      = (u16*)(ws + 17309696);
    u16*   V       = (u16*)(ws + 25698304);
    u16*   OT      = XT;

    k_stats<<<256, 256, 0, stream>>>(x, gamma, beta, coefA, coefB);
    k_fold<<<1024, 256, 0, stream>>>(wq, bq, wk, bk, wv, bv, wp, coefA, coefB,
                                     Wqkv, biasQKV, Wp16);
    k_transpose<<<dim3(64, 4, 4), 256, 0, stream>>>(x, XT);
    k_qkv<<<dim3(12, 64, 4), 256, 0, stream>>>(XT, Wqkv, biasQKV, QT, KT, V);
    k_attn<<<256, 256, 0, stream>>>(QT, KT, V, OT);
    k_proj<<<dim3(4, 64, 4), 256, 0, stream>>>(OT, Wp16, bp, x, out);
}

// Round 6
// 291.348 us; speedup vs baseline: 2.5199x; 1.3271x over previous
//
#include <hip/hip_runtime.h>
#include <math.h>

typedef unsigned short u16;
typedef unsigned int u32;
typedef short s16x8 __attribute__((ext_vector_type(8)));   // 8 bf16 (4 VGPRs)
typedef float f32x4 __attribute__((ext_vector_type(4)));   // 4 fp32 acc

static constexpr int Cc = 256;
static constexpr int Ll = 4096;
static constexpr int Bb = 4;

__device__ __forceinline__ u16 f2b(float f) {
    union { float f; unsigned u; } v; v.f = f;
    unsigned r = v.u + 0x7FFF + ((v.u >> 16) & 1);   // RNE
    return (u16)(r >> 16);
}
__device__ __forceinline__ float b2f(u16 h) {
    union { unsigned u; float f; } v; v.u = ((unsigned)h) << 16; return v.f;
}

// async 16B global->LDS (lds dest = wave-uniform base + lane*16)
__device__ __forceinline__ void gload_lds16(const u16* g, u16* l) {
    __builtin_amdgcn_global_load_lds(
        (const __attribute__((address_space(1))) u32*)g,
        (__attribute__((address_space(3))) u32*)l, 16, 0, 0);
}

// ---------------- Kernel 1: BN stats -> folded affine coefs ----------------
__global__ void k_stats(const float* __restrict__ x, const float* __restrict__ gamma,
                        const float* __restrict__ beta, float* __restrict__ coefA,
                        float* __restrict__ coefB) {
    int c = blockIdx.x, t = threadIdx.x;
    float s = 0.f, s2 = 0.f;
    for (int idx = t; idx < Bb * Ll; idx += 256) {
        int b = idx >> 12, l = idx & (Ll - 1);
        float v = x[(size_t)(b * Cc + c) * Ll + l];
        s += v; s2 += v * v;
    }
    __shared__ float rs[256], rs2[256];
    rs[t] = s; rs2[t] = s2; __syncthreads();
    for (int off = 128; off > 0; off >>= 1) {
        if (t < off) { rs[t] += rs[t + off]; rs2[t] += rs2[t + off]; }
        __syncthreads();
    }
    if (t == 0) {
        float mean = rs[0] / (Bb * Ll);
        float var  = rs2[0] / (Bb * Ll) - mean * mean;   // biased, as torch BN
        float rstd = rsqrtf(var + 1e-5f);
        float a = gamma[c] * rstd;
        coefA[c] = a;
        coefB[c] = beta[c] - mean * a;
    }
}

// ---------------- Kernel 2: fold BN into weights, convert bf16 ----------------
__global__ void k_fold(const float* __restrict__ wq, const float* __restrict__ bq,
                       const float* __restrict__ wk, const float* __restrict__ bk,
                       const float* __restrict__ wv, const float* __restrict__ bv,
                       const float* __restrict__ wp,
                       const float* __restrict__ coefA, const float* __restrict__ coefB,
                       u16* __restrict__ Wqkv, float* __restrict__ biasQKV,
                       u16* __restrict__ Wp16) {
    int m = blockIdx.x, t = threadIdx.x;
    if (m >= 768) {
        int row = m - 768;
        Wp16[row * Cc + t] = f2b(wp[row * Cc + t]);
        return;
    }
    int type = m >> 8, row = m & 255;
    const float* W  = (type == 0) ? wq : (type == 1) ? wk : wv;
    const float* bs = (type == 0) ? bq : (type == 1) ? bk : bv;
    float wval = W[row * Cc + t];
    float s2 = (type == 0) ? 0.09016844005556021f : 1.0f;  // (1/sqrt(C)) * log2(e)
    Wqkv[m * Cc + t] = f2b(wval * coefA[t] * s2);
    __shared__ float rs[256];
    rs[t] = wval * coefB[t];
    __syncthreads();
    for (int off = 128; off > 0; off >>= 1) {
        if (t < off) rs[t] += rs[t + off];
        __syncthreads();
    }
    if (t == 0) biasQKV[m] = (bs[row] + rs[0]) * s2;
}

// ---------------- Kernel 3: x [B][C][L] fp32 -> XT [B][L][C] bf16 ----------------
__global__ void k_transpose(const float* __restrict__ x, u16* __restrict__ XT) {
    int lt = blockIdx.x, ct = blockIdx.y, b = blockIdx.z, t = threadIdx.x;
    int l0 = lt * 64, c0 = ct * 64;
    __shared__ u16 tile[64][65];
    int ll = t & 63, cb = t >> 6;
    #pragma unroll
    for (int rep = 0; rep < 16; rep++) {
        int cl = cb * 16 + rep;
        tile[cl][ll] = f2b(x[(size_t)(b * Cc + c0 + cl) * Ll + l0 + ll]);
    }
    __syncthreads();
    int cl2 = t & 63, lb = t >> 6;
    #pragma unroll
    for (int rep = 0; rep < 16; rep++) {
        int ll2 = lb * 16 + rep;
        XT[(size_t)(b * Ll + l0 + ll2) * Cc + c0 + cl2] = tile[cl2][ll2];
    }
}

// ---------------- Kernel 4: QKV GEMM -> QT,KT [B][L][C], V [B][C][L] (all bf16) --
__launch_bounds__(256, 1)
__global__ void k_qkv(const u16* __restrict__ XT, const u16* __restrict__ Wqkv,
                      const float* __restrict__ biasQKV,
                      u16* __restrict__ QT, u16* __restrict__ KT, u16* __restrict__ V) {
    int ox = blockIdx.x, ly = blockIdx.y, b = blockIdx.z;
    int t = threadIdx.x, w = t >> 6, lane = t & 63;
    int l16 = lane & 15, quad = lane >> 4;
    int o0 = ox * 64, l0 = ly * 64;
    __shared__ u16 Xs[64][264];
    {
        int row = t >> 2, chunk = t & 3;
        const u16* src = XT + (size_t)(b * Ll + l0 + row) * Cc + chunk * 64;
        u16* dst = &Xs[row][chunk * 64];
        #pragma unroll
        for (int u = 0; u < 8; u++)
            *(uint4*)(dst + u * 8) = *(const uint4*)(src + u * 8);
    }
    s16x8 af[8];
    {
        const u16* wrow = Wqkv + (size_t)(o0 + w * 16 + l16) * Cc + quad * 8;
        #pragma unroll
        for (int ks = 0; ks < 8; ks++) af[ks] = *(const s16x8*)(wrow + ks * 32);
    }
    __syncthreads();
    f32x4 acc[4];
    #pragma unroll
    for (int ns = 0; ns < 4; ns++)
        #pragma unroll
        for (int r = 0; r < 4; r++) acc[ns][r] = 0.f;
    #pragma unroll
    for (int ks = 0; ks < 8; ks++) {
        #pragma unroll
        for (int ns = 0; ns < 4; ns++) {
            s16x8 bf = *(const s16x8*)(&Xs[ns * 16 + l16][ks * 32 + quad * 8]);
            acc[ns] = __builtin_amdgcn_mfma_f32_16x16x32_bf16(af[ks], bf, acc[ns], 0, 0, 0);
        }
    }
    int obase = o0 + w * 16 + quad * 4;
    float bias[4];
    #pragma unroll
    for (int r = 0; r < 4; r++) bias[r] = biasQKV[obase + r];
    #pragma unroll
    for (int ns = 0; ns < 4; ns++) {
        int l = l0 + ns * 16 + l16;
        if (ox < 8) {
            u16* dstbase = (ox < 4) ? QT : KT;
            int oo = obase - ((ox < 4) ? 0 : 256);
            ushort4 pk;
            pk.x = f2b(acc[ns][0] + bias[0]);
            pk.y = f2b(acc[ns][1] + bias[1]);
            pk.z = f2b(acc[ns][2] + bias[2]);
            pk.w = f2b(acc[ns][3] + bias[3]);
            *(ushort4*)(dstbase + (size_t)(b * Ll + l) * Cc + oo) = pk;
        } else {
            #pragma unroll
            for (int r = 0; r < 4; r++) {
                int o = obase + r - 512;
                V[(size_t)(b * Cc + o) * Ll + l] = f2b(acc[ns][r] + bias[r]);
            }
        }
    }
}

// ---------------- Kernel 5: flash attention, split-j -> partials ----------------
// 512 blocks = (b x 64 i-tiles x 2 j-halves); 4 waves x 16 rows; 32 j-tiles each.
// Two-phase K/V pipeline (Ka 32KB + Vb 32KB + Ps 9.2KB = 74.75KB -> 2 blocks/CU).
// Outputs UNNORMALIZED O (bf16) + per-row m,l (base-2) for the merge kernel.
__launch_bounds__(256, 2)
__global__ void k_attn(const u16* __restrict__ QT, const u16* __restrict__ KT,
                       const u16* __restrict__ V, u16* __restrict__ Opart,
                       float* __restrict__ Mpart, float* __restrict__ Lpart) {
    int id = blockIdx.x;
    int xcd = id & 7, local = id >> 3;
    int b = xcd >> 1;                       // 2 XCDs per batch: K/V L2-resident
    int u = local * 2 + (xcd & 1);          // 0..127
    int itile = u >> 1;
    int jh = u & 1;
    int t = threadIdx.x, w = t >> 6, lane = t & 63;
    int l16 = lane & 15, quad = lane >> 4;
    int i0 = itile * 64 + w * 16;

    __shared__ u16 Ka[16384];       // 32KB fragment-permuted K tile (phase A)
    __shared__ u16 Vbuf[16384];     // 32KB fragment-permuted V tile (phase B)
    __shared__ u16 Ps[4][16][72];   // per-wave P round-trip (9.2KB)

    s16x8 qf[8];
    {
        const u16* qrow = QT + (size_t)(b * Ll + i0 + l16) * Cc + quad * 8;
        #pragma unroll
        for (int ks = 0; ks < 8; ks++) qf[ks] = *(const s16x8*)(qrow + ks * 32);
    }

    const u16* Kb = KT + (size_t)b * Ll * Cc;
    const u16* Vg = V + (size_t)b * Cc * Ll;
    const u16* kptr[8];
    const u16* vptr[8];
    #pragma unroll
    for (int R = 0; R < 8; R++) {
        int g = R * 4 + w;
        int ns = g >> 3, ks = g & 7;
        kptr[R] = Kb + (size_t)(jh * 2048 + ns * 16 + l16) * Cc + ks * 32 + quad * 8;
        int nc = g >> 1, ks2 = g & 1;
        vptr[R] = Vg + (size_t)(nc * 16 + l16) * Ll + jh * 2048 + ks2 * 32 + quad * 8;
    }

    // prologue: issue K(first) and V(first)
    #pragma unroll
    for (int R = 0; R < 8; R++) {
        gload_lds16(kptr[R], &Ka[(size_t)(R * 256 + w * 64) * 8]);
        kptr[R] += 64 * Cc;
    }
    #pragma unroll
    for (int R = 0; R < 8; R++) {
        gload_lds16(vptr[R], &Vbuf[(size_t)(R * 256 + w * 64) * 8]);
        vptr[R] += 64;
    }

    f32x4 of[16];
    #pragma unroll
    for (int nc = 0; nc < 16; nc++)
        #pragma unroll
        for (int r = 0; r < 4; r++) of[nc][r] = 0.f;
    float m_run[4], lp[4];
    #pragma unroll
    for (int r = 0; r < 4; r++) { m_run[r] = -INFINITY; lp[r] = 0.f; }

    __syncthreads();   // P0: drains K(first), V(first)

    for (int it = 0; it < 32; it++) {
        // ---- phase A: S = Q K^T from Ka ----
        f32x4 sf[4];
        #pragma unroll
        for (int ns = 0; ns < 4; ns++)
            #pragma unroll
            for (int r = 0; r < 4; r++) sf[ns][r] = 0.f;
        #pragma unroll
        for (int ks = 0; ks < 8; ks++) {
            #pragma unroll
            for (int ns = 0; ns < 4; ns++) {
                s16x8 bf = *(const s16x8*)(&Ka[(size_t)((ns * 8 + ks) * 64 + lane) * 8]);
                sf[ns] = __builtin_amdgcn_mfma_f32_16x16x32_bf16(qf[ks], bf, sf[ns], 0, 0, 0);
            }
        }
        __syncthreads();   // M: Ka reads done; drains V(it) loads
        if (it < 31) {
            #pragma unroll
            for (int R = 0; R < 8; R++) {
                gload_lds16(kptr[R], &Ka[(size_t)(R * 256 + w * 64) * 8]);
                kptr[R] += 64 * Cc;
            }
        }
        // ---- online softmax (deferred l-reduction; gated O-rescale) ----
        float pv[4][4], al[4];
        bool need = false;
        #pragma unroll
        for (int r = 0; r < 4; r++) {
            float tm = fmaxf(fmaxf(sf[0][r], sf[1][r]), fmaxf(sf[2][r], sf[3][r]));
            #pragma unroll
            for (int off = 8; off > 0; off >>= 1) tm = fmaxf(tm, __shfl_xor(tm, off));
            float mnew = fmaxf(m_run[r], tm);
            al[r] = exp2f(m_run[r] - mnew);
            need = need || (mnew > m_run[r]);
            m_run[r] = mnew;
            float rsum = 0.f;
            #pragma unroll
            for (int ns = 0; ns < 4; ns++) {
                float p = exp2f(sf[ns][r] - mnew);
                pv[ns][r] = p; rsum += p;
            }
            lp[r] = lp[r] * al[r] + rsum;   // per-lane partial; reduced at the end
        }
        if (__any(need)) {
            #pragma unroll
            for (int nc = 0; nc < 16; nc++)
                #pragma unroll
                for (int r = 0; r < 4; r++) of[nc][r] *= al[r];
        }
        // ---- P: C/D layout -> LDS -> A layout (wave-private) ----
        #pragma unroll
        for (int ns = 0; ns < 4; ns++)
            #pragma unroll
            for (int r = 0; r < 4; r++)
                Ps[w][quad * 4 + r][ns * 16 + l16] = f2b(pv[ns][r]);
        // ---- phase B: O += P * V^T from Vbuf ----
        #pragma unroll
        for (int ks2 = 0; ks2 < 2; ks2++) {
            s16x8 pa = *(const s16x8*)(&Ps[w][l16][ks2 * 32 + quad * 8]);
            #pragma unroll
            for (int nc = 0; nc < 16; nc++) {
                s16x8 bf = *(const s16x8*)(&Vbuf[(size_t)((nc * 2 + ks2) * 64 + lane) * 8]);
                of[nc] = __builtin_amdgcn_mfma_f32_16x16x32_bf16(pa, bf, of[nc], 0, 0, 0);
            }
        }
        __syncthreads();   // B: Vbuf reads done; drains K(it+1) loads
        if (it < 31) {
            #pragma unroll
            for (int R = 0; R < 8; R++) {
                gload_lds16(vptr[R], &Vbuf[(size_t)(R * 256 + w * 64) * 8]);
                vptr[R] += 64;
            }
        }
    }
    // final l reduction across the 16-lane quad group; write m,l,O(unnormalized)
    int mi = ((jh * 4 + b) * 64 + itile) * 64 + w * 16 + quad * 4;
    #pragma unroll
    for (int r = 0; r < 4; r++) {
        float ls = lp[r];
        #pragma unroll
        for (int off = 8; off > 0; off >>= 1) ls += __shfl_xor(ls, off);
        if (l16 == 0) {
            Mpart[mi + r] = m_run[r];
            Lpart[mi + r] = ls;
        }
    }
    #pragma unroll
    for (int nc = 0; nc < 16; nc++)
        #pragma unroll
        for (int r = 0; r < 4; r++)
            Opart[(size_t)(mi + r) * 256 + nc * 16 + l16] = f2b(of[nc][r]);
}

// ---------------- Kernel 5b: merge the two j-half partials -> OT bf16 ----------
__global__ void k_merge(const u16* __restrict__ Opart, const float* __restrict__ Mpart,
                        const float* __restrict__ Lpart, u16* __restrict__ OT) {
    int id = blockIdx.x, t = threadIdx.x;
    int b = id >> 6, itile = id & 63;
    int row = t >> 2, seg = t & 3;
    int i0 = ((0 + b) * 64 + itile) * 64 + row;
    int i1 = ((4 + b) * 64 + itile) * 64 + row;
    float m0 = Mpart[i0], m1 = Mpart[i1];
    float l0 = Lpart[i0], l1 = Lpart[i1];
    float mx = fmaxf(m0, m1);
    float w0 = exp2f(m0 - mx), w1 = exp2f(m1 - mx);
    float inv = 1.f / (l0 * w0 + l1 * w1);
    w0 *= inv; w1 *= inv;
    const u16* p0 = Opart + (size_t)i0 * 256 + seg * 64;
    const u16* p1 = Opart + (size_t)i1 * 256 + seg * 64;
    u16* dst = OT + (size_t)(b * Ll + itile * 64 + row) * Cc + seg * 64;
    #pragma unroll
    for (int k = 0; k < 8; k++) {
        ushort4 a0 = *(const ushort4*)(p0 + k * 8 + 0);
        ushort4 b0 = *(const ushort4*)(p0 + k * 8 + 4);
        ushort4 a1 = *(const ushort4*)(p1 + k * 8 + 0);
        ushort4 b1 = *(const ushort4*)(p1 + k * 8 + 4);
        ushort4 oA, oB;
        oA.x = f2b(b2f(a0.x) * w0 + b2f(a1.x) * w1);
        oA.y = f2b(b2f(a0.y) * w0 + b2f(a1.y) * w1);
        oA.z = f2b(b2f(a0.z) * w0 + b2f(a1.z) * w1);
        oA.w = f2b(b2f(a0.w) * w0 + b2f(a1.w) * w1);
        oB.x = f2b(b2f(b0.x) * w0 + b2f(b1.x) * w1);
        oB.y = f2b(b2f(b0.y) * w0 + b2f(b1.y) * w1);
        oB.z = f2b(b2f(b0.z) * w0 + b2f(b1.z) * w1);
        oB.w = f2b(b2f(b0.w) * w0 + b2f(b1.w) * w1);
        *(ushort4*)(dst + k * 8 + 0) = oA;
        *(ushort4*)(dst + k * 8 + 4) = oB;
    }
}

// ---------------- Kernel 6: projection + bias + residual -> out fp32 ----------------
__launch_bounds__(256, 1)
__global__ void k_proj(const u16* __restrict__ OT, const u16* __restrict__ Wp16,
                       const float* __restrict__ bp, const float* __restrict__ x,
                       float* __restrict__ out) {
    int ox = blockIdx.x, ly = blockIdx.y, b = blockIdx.z;
    int t = threadIdx.x, w = t >> 6, lane = t & 63;
    int l16 = lane & 15, quad = lane >> 4;
    int o0 = ox * 64, l0 = ly * 64;
    __shared__ u16 Os[64][264];
    {
        int row = t >> 2, chunk = t & 3;
        const u16* src = OT + (size_t)(b * Ll + l0 + row) * Cc + chunk * 64;
        u16* dst = &Os[row][chunk * 64];
        #pragma unroll
        for (int u = 0; u < 8; u++)
            *(uint4*)(dst + u * 8) = *(const uint4*)(src + u * 8);
    }
    s16x8 af[8];
    {
        const u16* wrow = Wp16 + (size_t)(o0 + w * 16 + l16) * Cc + quad * 8;
        #pragma unroll
        for (int ks = 0; ks < 8; ks++) af[ks] = *(const s16x8*)(wrow + ks * 32);
    }
    __syncthreads();
    f32x4 acc[4];
    #pragma unroll
    for (int ns = 0; ns < 4; ns++)
        #pragma unroll
        for (int r = 0; r < 4; r++) acc[ns][r] = 0.f;
    #pragma unroll
    for (int ks = 0; ks < 8; ks++) {
        #pragma unroll
        for (int ns = 0; ns < 4; ns++) {
            s16x8 bf = *(const s16x8*)(&Os[ns * 16 + l16][ks * 32 + quad * 8]);
            acc[ns] = __builtin_amdgcn_mfma_f32_16x16x32_bf16(af[ks], bf, acc[ns], 0, 0, 0);
        }
    }
    int ob = o0 + w * 16 + quad * 4;
    float bias[4];
    #pragma unroll
    for (int r = 0; r < 4; r++) bias[r] = bp[ob + r];
    #pragma unroll
    for (int ns = 0; ns < 4; ns++) {
        #pragma unroll
        for (int r = 0; r < 4; r++) {
            int o = ob + r;
            int l = l0 + ns * 16 + l16;
            size_t idx = (size_t)(b * Cc + o) * Ll + l;
            out[idx] = x[idx] + bias[r] + acc[ns][r];
        }
    }
}

// ---------------- launch ----------------
extern "C" void kernel_launch(void* const* d_in, const int* in_sizes, int n_in,
                              void* d_out, int out_size, void* d_ws, size_t ws_size,
                              hipStream_t stream) {
    const float* x     = (const float*)d_in[0];
    const float* gamma = (const float*)d_in[1];
    const float* beta  = (const float*)d_in[2];
    const float* wq    = (const float*)d_in[3];
    const float* bq    = (const float*)d_in[4];
    const float* wk    = (const float*)d_in[5];
    const float* bk    = (const float*)d_in[6];
    const float* wv    = (const float*)d_in[7];
    const float* bv    = (const float*)d_in[8];
    const float* wp    = (const float*)d_in[9];
    const float* bp    = (const float*)d_in[10];
    float* out = (float*)d_out;
    char* ws = (char*)d_ws;

    float* coefA   = (float*)(ws + 0);
    float* coefB   = (float*)(ws + 1024);
    float* biasQKV = (float*)(ws + 2048);
    u16*   Wqkv    = (u16*)(ws + 8192);
    u16*   Wp16    = (u16*)(ws + 401408);
    u16*   XT      = (u16*)(ws + 532480);      // [B][L][C] bf16 (8.39MB)
    u16*   QT      = (u16*)(ws + 8921088);
    u16*   KT      = (u16*)(ws + 17309696);
    u16*   V       = (u16*)(ws + 25698304);
    float* Mpart   = (float*)(ws + 34086912);  // 512*64 f32 = 128KB... (2*4*64*64)
    float* Lpart   = (float*)(ws + 34218240);  // 128KB... actually 131072 B each
    u16*   OT      = XT;                       // alias: XT dead after k_qkv
    u16*   Opart   = (u16*)d_out;              // 16.78MB scratch, overwritten by k_proj

    k_stats<<<256, 256, 0, stream>>>(x, gamma, beta, coefA, coefB);
    k_fold<<<1024, 256, 0, stream>>>(wq, bq, wk, bk, wv, bv, wp, coefA, coefB,
                                     Wqkv, biasQKV, Wp16);
    k_transpose<<<dim3(64, 4, 4), 256, 0, stream>>>(x, XT);
    k_qkv<<<dim3(12, 64, 4), 256, 0, stream>>>(XT, Wqkv, biasQKV, QT, KT, V);
    k_attn<<<512, 256, 0, stream>>>(QT, KT, V, Opart, Mpart, Lpart);
    k_merge<<<256, 256, 0, stream>>>(Opart, Mpart, Lpart, OT);
    k_proj<<<dim3(4, 64, 4), 256, 0, stream>>>(OT, Wp16, bp, x, out);
}